// Round 1
// baseline (795.837 us; speedup 1.0000x reference)
//
#include <hip/hip_runtime.h>
#include <cstdint>
#include <cstddef>

// GNNGuard: 2-layer GCN, N=100000 nodes, E=1.6M edges, 512->128->16, log_softmax.
// Pipeline: GEMM1 (bf16 MFMA, no LDS) -> CSR build -> pull aggregation (wave/node)
//           -> GEMM2 (LDS) -> fused agg2+bias+log_softmax.

#define NFEAT 512
#define NHID 128
#define NCLASS 16

typedef __attribute__((ext_vector_type(8))) __bf16 bf16x8;
typedef __attribute__((ext_vector_type(4))) float f32x4;

// ---------------- W1 pre-pack into MFMA B-fragment order ----------------
// Layout: [kstep 0..15][nchunk 0..7][lane 0..63][j 0..7]
// value = bf16( W1[k = kstep*32 + (lane>>4)*8 + j][n = nchunk*16 + (lane&15)] )
__global__ void k_prep_w1(const float* __restrict__ W1, __bf16* __restrict__ W1f) {
    int t = blockIdx.x * 256 + threadIdx.x;
    if (t >= 16 * 8 * 64) return;
    int lane = t & 63;
    int nc = (t >> 6) & 7;
    int ks = t >> 9;
    int q = lane >> 4, col = lane & 15;
    __bf16* outp = W1f + (size_t)t * 8;
#pragma unroll
    for (int j = 0; j < 8; j++) {
        int k = ks * 32 + q * 8 + j;
        int n = nc * 16 + col;
        outp[j] = (__bf16)W1[k * NHID + n];
    }
}

// ---------------- CSR build ----------------
__global__ void k_count(const int* __restrict__ dst, int* __restrict__ cnt, int E) {
    int e = blockIdx.x * 256 + threadIdx.x;
    if (e < E) atomicAdd(&cnt[dst[e]], 1);
}

// single-block exclusive scan over N counts -> row_ptr (and a second copy for fill)
__global__ void k_scan(const int* __restrict__ cnt, int* __restrict__ rp,
                       int* __restrict__ woff, int N) {
    __shared__ int wsum[16];
    int t = threadIdx.x;
    int lane = t & 63, w = t >> 6;
    int running = 0;
    for (int base = 0; base < N; base += 1024) {
        int i = base + t;
        int v = (i < N) ? cnt[i] : 0;
        int xv = v;
#pragma unroll
        for (int o = 1; o < 64; o <<= 1) {
            int y = __shfl_up(xv, o);
            if (lane >= o) xv += y;
        }
        if (lane == 63) wsum[w] = xv;
        __syncthreads();
        int wpre = 0;
        for (int j = 0; j < w; j++) wpre += wsum[j];
        int total = 0;
        for (int j = 0; j < 16; j++) total += wsum[j];
        if (i < N) {
            int excl = running + wpre + xv - v;
            rp[i] = excl;
            woff[i] = excl;
        }
        running += total;
        __syncthreads();
    }
    if (t == 0) rp[N] = running;
}

__global__ void k_fill(const int* __restrict__ src, const int* __restrict__ dst,
                       const float* __restrict__ ew, int* __restrict__ woff,
                       int* __restrict__ csrc, float* __restrict__ cw, int E) {
    int e = blockIdx.x * 256 + threadIdx.x;
    if (e < E) {
        int d = dst[e];
        int p = atomicAdd(&woff[d], 1);
        csrc[p] = src[e];
        cw[p] = ew[e];
    }
}

// ---------------- GEMM1: h1[M,128] = x[M,512] @ W1  (bf16 MFMA, no LDS) ----------------
// Block 256 = 4 waves; each wave: 16 rows x 128 cols, K-loop 512 in steps of 32.
// A frag: lane holds x[m = Mbase + 16w + (lane&15)][kk + (lane>>4)*8 + j], fp32->bf16 inline.
// B frag: coalesced dwordx4 from pre-packed W1f (L2 resident).
// C/D:    col = lane&15, row = (lane>>4)*4 + reg   [verified layout, learn_hip m89/m91]
__global__ void k_gemm1(const float* __restrict__ x, const __bf16* __restrict__ W1f,
                        float* __restrict__ h1, int M) {
    int wave = threadIdx.x >> 6;
    int lane = threadIdx.x & 63;
    int q = lane >> 4;
    int col = lane & 15;
    int m0 = blockIdx.x * 64 + wave * 16 + col;  // A-operand row for this lane
    bool valid = (m0 < M);

    f32x4 acc[8];
#pragma unroll
    for (int n = 0; n < 8; n++) acc[n] = (f32x4)(0.0f);

    const bf16x8* Bf = (const bf16x8*)W1f;
    const float* arow = x + (size_t)m0 * NFEAT + q * 8;

    for (int kk = 0; kk < NFEAT; kk += 32) {
        bf16x8 af;
        if (valid) {
            const float4* ap = (const float4*)(arow + kk);
            float4 a0 = ap[0];
            float4 a1 = ap[1];
            af[0] = (__bf16)a0.x; af[1] = (__bf16)a0.y;
            af[2] = (__bf16)a0.z; af[3] = (__bf16)a0.w;
            af[4] = (__bf16)a1.x; af[5] = (__bf16)a1.y;
            af[6] = (__bf16)a1.z; af[7] = (__bf16)a1.w;
        } else {
#pragma unroll
            for (int j = 0; j < 8; j++) af[j] = (__bf16)0.0f;
        }
        int kb = (kk >> 5) * 8;
#pragma unroll
        for (int n = 0; n < 8; n++) {
            bf16x8 bf = Bf[(size_t)(kb + n) * 64 + lane];
            acc[n] = __builtin_amdgcn_mfma_f32_16x16x32_bf16(af, bf, acc[n], 0, 0, 0);
        }
    }

    int rbase = blockIdx.x * 64 + wave * 16 + q * 4;
#pragma unroll
    for (int r = 0; r < 4; r++) {
        int row = rbase + r;
        if (row < M) {
            float* op = h1 + (size_t)row * NHID + col;
#pragma unroll
            for (int n = 0; n < 8; n++) op[n * 16] = acc[n][r];
        }
    }
}

// ---------------- Aggregation layer 1 (pull, wave per node) + bias + ReLU ----------------
__global__ void k_agg1(const float* __restrict__ h1, const int* __restrict__ rp,
                       const int* __restrict__ csrc, const float* __restrict__ cw,
                       const float* __restrict__ b1, float* __restrict__ h, int N) {
    int gw = (int)((blockIdx.x * (unsigned)blockDim.x + threadIdx.x) >> 6);  // node id
    int lane = threadIdx.x & 63;
    if (gw >= N) return;
    int s0 = rp[gw], s1 = rp[gw + 1];
    float ax = 0.f, ay = 0.f;
    for (int base = s0; base < s1; base += 64) {
        int cnt = s1 - base;
        if (cnt > 64) cnt = 64;
        int sv = 0;
        float wv = 0.f;
        if (lane < cnt) {
            sv = csrc[base + lane];
            wv = cw[base + lane];
        }
        for (int j = 0; j < cnt; j++) {
            int s = __shfl(sv, j);
            float ww = __shfl(wv, j);
            const float2* hp = (const float2*)(h1 + (size_t)s * NHID);
            float2 hv = hp[lane];
            ax = fmaf(ww, hv.x, ax);
            ay = fmaf(ww, hv.y, ay);
        }
    }
    float2 o;
    o.x = fmaxf(ax + b1[lane * 2 + 0], 0.f);
    o.y = fmaxf(ay + b1[lane * 2 + 1], 0.f);
    ((float2*)(h + (size_t)gw * NHID))[lane] = o;
}

// ---------------- GEMM2: h2[M,16] = h[M,128] @ W2 ----------------
__global__ void k_gemm2(const float* __restrict__ h, const float* __restrict__ W2,
                        float* __restrict__ h2, int N) {
    __shared__ float W2s[NHID * NCLASS];
    __shared__ float hs[16][NHID + 4];
    int t = threadIdx.x;
#pragma unroll
    for (int j = 0; j < 8; j++) W2s[t * 8 + j] = W2[t * 8 + j];
    int nb = blockIdx.x * 16;
    {
        int idx = t * 8;
        int row = idx >> 7;
        int k = idx & 127;
        if (nb + row < N) {
            const float* src = h + (size_t)(nb + row) * NHID + k;
            float4 v0 = *(const float4*)(src);
            float4 v1 = *(const float4*)(src + 4);
            hs[row][k + 0] = v0.x; hs[row][k + 1] = v0.y;
            hs[row][k + 2] = v0.z; hs[row][k + 3] = v0.w;
            hs[row][k + 4] = v1.x; hs[row][k + 5] = v1.y;
            hs[row][k + 6] = v1.z; hs[row][k + 7] = v1.w;
        } else {
#pragma unroll
            for (int j = 0; j < 8; j++) hs[row][k + j] = 0.f;
        }
    }
    __syncthreads();
    int ni = t >> 4, c = t & 15;
    float acc = 0.f;
#pragma unroll 8
    for (int k = 0; k < NHID; k++) acc = fmaf(hs[ni][k], W2s[k * NCLASS + c], acc);
    if (nb + ni < N) h2[(size_t)(nb + ni) * NCLASS + c] = acc;
}

// ---------------- Aggregation layer 2 + bias + log_softmax (16 lanes / node) ----------------
__global__ void k_agg2(const float* __restrict__ h2, const int* __restrict__ rp,
                       const int* __restrict__ csrc, const float* __restrict__ cw,
                       const float* __restrict__ b2, float* __restrict__ out, int N) {
    int t = blockIdx.x * 256 + threadIdx.x;
    int node = t >> 4;
    int c = t & 15;
    if (node >= N) return;
    int s0 = rp[node], s1 = rp[node + 1];
    float acc = 0.f;
    for (int i = s0; i < s1; i++) {
        int s = csrc[i];
        float w = cw[i];
        acc = fmaf(w, h2[(size_t)s * NCLASS + c], acc);
    }
    float o = acc + b2[c];
    float m = o;
#pragma unroll
    for (int d = 1; d < 16; d <<= 1) m = fmaxf(m, __shfl_xor(m, d));
    float e = expf(o - m);
    float ssum = e;
#pragma unroll
    for (int d = 1; d < 16; d <<= 1) ssum += __shfl_xor(ssum, d);
    out[(size_t)node * NCLASS + c] = o - m - logf(ssum);
}

extern "C" void kernel_launch(void* const* d_in, const int* in_sizes, int n_in,
                              void* d_out, int out_size, void* d_ws, size_t ws_size,
                              hipStream_t stream) {
    const float* x  = (const float*)d_in[0];
    const int*   ei = (const int*)d_in[1];
    const float* ew = (const float*)d_in[2];
    const float* W1 = (const float*)d_in[3];
    const float* b1 = (const float*)d_in[4];
    const float* W2 = (const float*)d_in[5];
    const float* b2 = (const float*)d_in[6];
    float* out = (float*)d_out;

    int N = in_sizes[0] / NFEAT;   // 100000
    int E = in_sizes[2];           // 1600000
    const int* srcI = ei;
    const int* dstI = ei + E;

    // workspace carve-out (~123 MB)
    char* p = (char*)d_ws;
    auto alloc = [&](size_t bytes) {
        char* r = p;
        p += (bytes + 511) & ~(size_t)511;
        return r;
    };
    float*  h1   = (float*)alloc((size_t)N * NHID * 4);
    float*  h    = (float*)alloc((size_t)N * NHID * 4);
    float*  h2   = (float*)alloc((size_t)N * NCLASS * 4);
    int*    cnt  = (int*)alloc((size_t)N * 4);
    int*    rp   = (int*)alloc(((size_t)N + 1) * 4);
    int*    woff = (int*)alloc((size_t)N * 4);
    int*    csrc = (int*)alloc((size_t)E * 4);
    float*  cw   = (float*)alloc((size_t)E * 4);
    __bf16* W1f  = (__bf16*)alloc((size_t)NFEAT * NHID * 2);

    hipMemsetAsync(cnt, 0, (size_t)N * 4, stream);
    k_prep_w1<<<32, 256, 0, stream>>>(W1, W1f);

    int eb = (E + 255) / 256;
    k_count<<<eb, 256, 0, stream>>>(dstI, cnt, E);
    k_scan<<<1, 1024, 0, stream>>>(cnt, rp, woff, N);
    k_fill<<<eb, 256, 0, stream>>>(srcI, dstI, ew, woff, csrc, cw, E);

    k_gemm1<<<(N + 63) / 64, 256, 0, stream>>>(x, W1f, h1, N);
    k_agg1<<<(N + 3) / 4, 256, 0, stream>>>(h1, rp, csrc, cw, b1, h, N);
    k_gemm2<<<(N + 15) / 16, 256, 0, stream>>>(h, W2, h2, N);
    k_agg2<<<(int)(((size_t)N * 16 + 255) / 256), 256, 0, stream>>>(h2, rp, csrc, cw, b2, out, N);
}

// Round 2
// 686.693 us; speedup vs baseline: 1.1589x; 1.1589x over previous
//
#include <hip/hip_runtime.h>
#include <cstdint>
#include <cstddef>

// GNNGuard: 2-layer GCN, N=100000 nodes, E=1.6M edges, 512->128->16, log_softmax.
// R2: multi-block scan (was single-block, ~hundreds of µs), bf16 h1/h to halve
// gather traffic, int2 CSR payload (single 8B scatter in fill).

#define NFEAT 512
#define NHID 128
#define NCLASS 16

typedef __attribute__((ext_vector_type(8))) __bf16 bf16x8;
typedef __attribute__((ext_vector_type(4))) float f32x4;

// ---------------- W1 pre-pack into MFMA B-fragment order ----------------
// Layout: [kstep 0..15][nchunk 0..7][lane 0..63][j 0..7]
// value = bf16( W1[k = kstep*32 + (lane>>4)*8 + j][n = nchunk*16 + (lane&15)] )
__global__ void k_prep_w1(const float* __restrict__ W1, __bf16* __restrict__ W1f) {
    int t = blockIdx.x * 256 + threadIdx.x;
    if (t >= 16 * 8 * 64) return;
    int lane = t & 63;
    int nc = (t >> 6) & 7;
    int ks = t >> 9;
    int q = lane >> 4, col = lane & 15;
    __bf16* outp = W1f + (size_t)t * 8;
#pragma unroll
    for (int j = 0; j < 8; j++) {
        int k = ks * 32 + q * 8 + j;
        int n = nc * 16 + col;
        outp[j] = (__bf16)W1[k * NHID + n];
    }
}

// ---------------- CSR build ----------------
__global__ void k_count(const int* __restrict__ dst, int* __restrict__ cnt, int E) {
    int e = blockIdx.x * 256 + threadIdx.x;
    if (e < E) atomicAdd(&cnt[dst[e]], 1);
}

// Block-level partial sums: block b sums cnt[b*1024 .. b*1024+1023]
__global__ void k_bsum(const int* __restrict__ cnt, int* __restrict__ bs, int N) {
    int b = blockIdx.x, t = threadIdx.x;  // 256 threads
    int base = b * 1024 + t * 4;
    int s = 0;
    if (base + 3 < N) {
        int4 v = *(const int4*)(cnt + base);
        s = v.x + v.y + v.z + v.w;
    } else {
        for (int j = 0; j < 4; j++) { int i = base + j; if (i < N) s += cnt[i]; }
    }
#pragma unroll
    for (int o = 32; o; o >>= 1) s += __shfl_down(s, o);
    __shared__ int ws[4];
    if ((t & 63) == 0) ws[t >> 6] = s;
    __syncthreads();
    if (t == 0) bs[b] = ws[0] + ws[1] + ws[2] + ws[3];
}

// Scan of NB (<=128) block sums in one block of 128 threads; writes rp[N]=total.
__global__ void k_bscan(const int* __restrict__ bs, int* __restrict__ bo,
                        int* __restrict__ rp, int NB, int N) {
    int t = threadIdx.x;
    int lane = t & 63;
    int v = (t < NB) ? bs[t] : 0;
    int x = v;
#pragma unroll
    for (int o = 1; o < 64; o <<= 1) { int y = __shfl_up(x, o); if (lane >= o) x += y; }
    __shared__ int w0;
    if (t == 63) w0 = x;
    __syncthreads();
    int pre = (t >= 64) ? w0 : 0;
    if (t < NB) bo[t] = pre + x - v;
    if (t == 127) rp[N] = pre + x;  // grand total
}

// Per-block scan + add block offset; writes rp and woff.
__global__ void k_cscan(const int* __restrict__ cnt, const int* __restrict__ bo,
                        int* __restrict__ rp, int* __restrict__ woff, int N) {
    int b = blockIdx.x, t = threadIdx.x;  // 256 threads
    int base = b * 1024 + t * 4;
    int v0 = 0, v1 = 0, v2 = 0, v3 = 0;
    if (base + 3 < N) {
        int4 v = *(const int4*)(cnt + base);
        v0 = v.x; v1 = v.y; v2 = v.z; v3 = v.w;
    } else {
        if (base + 0 < N) v0 = cnt[base + 0];
        if (base + 1 < N) v1 = cnt[base + 1];
        if (base + 2 < N) v2 = cnt[base + 2];
        if (base + 3 < N) v3 = cnt[base + 3];
    }
    int s = v0 + v1 + v2 + v3;
    int x = s;
    int lane = t & 63, w = t >> 6;
#pragma unroll
    for (int o = 1; o < 64; o <<= 1) { int y = __shfl_up(x, o); if (lane >= o) x += y; }
    __shared__ int ws[4];
    if (lane == 63) ws[w] = x;
    __syncthreads();
    int pre = 0;
    for (int j = 0; j < w; j++) pre += ws[j];
    int excl = bo[b] + pre + x - s;
    int4 r;
    r.x = excl; r.y = excl + v0; r.z = r.y + v1; r.w = r.z + v2;
    if (base + 3 < N) {
        *(int4*)(rp + base) = r;
        *(int4*)(woff + base) = r;
    } else {
        if (base + 0 < N) { rp[base + 0] = r.x; woff[base + 0] = r.x; }
        if (base + 1 < N) { rp[base + 1] = r.y; woff[base + 1] = r.y; }
        if (base + 2 < N) { rp[base + 2] = r.z; woff[base + 2] = r.z; }
        if (base + 3 < N) { rp[base + 3] = r.w; woff[base + 3] = r.w; }
    }
}

// Fill CSR payload: one 8B store per edge (src, weight-bits).
__global__ void k_fill(const int* __restrict__ src, const int* __restrict__ dst,
                       const float* __restrict__ ew, int* __restrict__ woff,
                       int2* __restrict__ pay, int E) {
    int e = blockIdx.x * 256 + threadIdx.x;
    if (e < E) {
        int d = dst[e];
        int p = atomicAdd(&woff[d], 1);
        int2 pv;
        pv.x = src[e];
        pv.y = __float_as_int(ew[e]);
        pay[p] = pv;
    }
}

// ---------------- GEMM1: h1b[M,128] = bf16( x[M,512] @ W1 )  (bf16 MFMA, no LDS) ----
// C/D: col = lane&15, row = (lane>>4)*4 + reg   [verified layout, learn_hip m89/m91]
__global__ void k_gemm1(const float* __restrict__ x, const __bf16* __restrict__ W1f,
                        __bf16* __restrict__ h1b, int M) {
    int wave = threadIdx.x >> 6;
    int lane = threadIdx.x & 63;
    int q = lane >> 4;
    int col = lane & 15;
    int m0 = blockIdx.x * 64 + wave * 16 + col;  // A-operand row for this lane
    bool valid = (m0 < M);

    f32x4 acc[8];
#pragma unroll
    for (int n = 0; n < 8; n++) acc[n] = (f32x4)(0.0f);

    const bf16x8* Bf = (const bf16x8*)W1f;
    const float* arow = x + (size_t)m0 * NFEAT + q * 8;

    for (int kk = 0; kk < NFEAT; kk += 32) {
        bf16x8 af;
        if (valid) {
            const float4* ap = (const float4*)(arow + kk);
            float4 a0 = ap[0];
            float4 a1 = ap[1];
            af[0] = (__bf16)a0.x; af[1] = (__bf16)a0.y;
            af[2] = (__bf16)a0.z; af[3] = (__bf16)a0.w;
            af[4] = (__bf16)a1.x; af[5] = (__bf16)a1.y;
            af[6] = (__bf16)a1.z; af[7] = (__bf16)a1.w;
        } else {
#pragma unroll
            for (int j = 0; j < 8; j++) af[j] = (__bf16)0.0f;
        }
        int kb = (kk >> 5) * 8;
#pragma unroll
        for (int n = 0; n < 8; n++) {
            bf16x8 bf = Bf[(size_t)(kb + n) * 64 + lane];
            acc[n] = __builtin_amdgcn_mfma_f32_16x16x32_bf16(af, bf, acc[n], 0, 0, 0);
        }
    }

    int rbase = blockIdx.x * 64 + wave * 16 + q * 4;
#pragma unroll
    for (int r = 0; r < 4; r++) {
        int row = rbase + r;
        if (row < M) {
            __bf16* op = h1b + (size_t)row * NHID + col;
#pragma unroll
            for (int n = 0; n < 8; n++) op[n * 16] = (__bf16)acc[n][r];
        }
    }
}

// ---------------- Aggregation layer 1 (pull, wave per node) + bias + ReLU -> bf16 ----
__global__ void k_agg1(const uint32_t* __restrict__ h1u, const int* __restrict__ rp,
                       const int2* __restrict__ pay, const float* __restrict__ b1,
                       uint32_t* __restrict__ hu, int N) {
    int gw = (int)((blockIdx.x * (unsigned)blockDim.x + threadIdx.x) >> 6);  // node id
    int lane = threadIdx.x & 63;
    if (gw >= N) return;
    int s0 = rp[gw], s1 = rp[gw + 1];
    float ax = 0.f, ay = 0.f;
    for (int base = s0; base < s1; base += 64) {
        int cnt = s1 - base;
        if (cnt > 64) cnt = 64;
        int sv = 0;
        float wv = 0.f;
        if (lane < cnt) {
            int2 pv = pay[base + lane];
            sv = pv.x;
            wv = __int_as_float(pv.y);
        }
        for (int j = 0; j < cnt; j++) {
            int s = __shfl(sv, j);
            float ww = __shfl(wv, j);
            uint32_t u = h1u[(size_t)s * 64 + lane];  // 2 bf16 features: 2*lane, 2*lane+1
            float fx = __uint_as_float(u << 16);
            float fy = __uint_as_float(u & 0xffff0000u);
            ax = fmaf(ww, fx, ax);
            ay = fmaf(ww, fy, ay);
        }
    }
    float2 bb = ((const float2*)b1)[lane];
    float ox = fmaxf(ax + bb.x, 0.f);
    float oy = fmaxf(ay + bb.y, 0.f);
    union { __bf16 h[2]; uint32_t u; } cvt;
    cvt.h[0] = (__bf16)ox;
    cvt.h[1] = (__bf16)oy;
    hu[(size_t)gw * 64 + lane] = cvt.u;
}

// ---------------- GEMM2: h2[M,16] = (bf16 h)[M,128] @ W2 ----------------
__global__ void k_gemm2(const uint32_t* __restrict__ hu, const float* __restrict__ W2,
                        float* __restrict__ h2, int N) {
    __shared__ float W2s[NHID * NCLASS];
    __shared__ float hs[16][NHID + 4];
    int t = threadIdx.x;
#pragma unroll
    for (int j = 0; j < 8; j++) W2s[t * 8 + j] = W2[t * 8 + j];
    int nb = blockIdx.x * 16;
    {
        // 16 rows x 64 uints = 1024 uints; 4 per thread
        int idx = t * 4;
        int row = idx >> 6;
        int kp = idx & 63;  // uint index within row (feature pair)
        if (nb + row < N) {
            const uint32_t* srcp = hu + (size_t)(nb + row) * 64 + kp;
#pragma unroll
            for (int j = 0; j < 4; j++) {
                uint32_t u = srcp[j];
                hs[row][(kp + j) * 2 + 0] = __uint_as_float(u << 16);
                hs[row][(kp + j) * 2 + 1] = __uint_as_float(u & 0xffff0000u);
            }
        } else {
#pragma unroll
            for (int j = 0; j < 4; j++) {
                hs[row][(kp + j) * 2 + 0] = 0.f;
                hs[row][(kp + j) * 2 + 1] = 0.f;
            }
        }
    }
    __syncthreads();
    int ni = t >> 4, c = t & 15;
    float acc = 0.f;
#pragma unroll 8
    for (int k = 0; k < NHID; k++) acc = fmaf(hs[ni][k], W2s[k * NCLASS + c], acc);
    if (nb + ni < N) h2[(size_t)(nb + ni) * NCLASS + c] = acc;
}

// ---------------- Aggregation layer 2 + bias + log_softmax (16 lanes / node) --------
__global__ void k_agg2(const float* __restrict__ h2, const int* __restrict__ rp,
                       const int2* __restrict__ pay, const float* __restrict__ b2,
                       float* __restrict__ out, int N) {
    int t = blockIdx.x * 256 + threadIdx.x;
    int node = t >> 4;
    int c = t & 15;
    if (node >= N) return;
    int s0 = rp[node], s1 = rp[node + 1];
    float acc = 0.f;
    for (int i = s0; i < s1; i++) {
        int2 pv = pay[i];
        acc = fmaf(__int_as_float(pv.y), h2[(size_t)pv.x * NCLASS + c], acc);
    }
    float o = acc + b2[c];
    float m = o;
#pragma unroll
    for (int d = 1; d < 16; d <<= 1) m = fmaxf(m, __shfl_xor(m, d));
    float e = expf(o - m);
    float ssum = e;
#pragma unroll
    for (int d = 1; d < 16; d <<= 1) ssum += __shfl_xor(ssum, d);
    out[(size_t)node * NCLASS + c] = o - m - logf(ssum);
}

extern "C" void kernel_launch(void* const* d_in, const int* in_sizes, int n_in,
                              void* d_out, int out_size, void* d_ws, size_t ws_size,
                              hipStream_t stream) {
    const float* x  = (const float*)d_in[0];
    const int*   ei = (const int*)d_in[1];
    const float* ew = (const float*)d_in[2];
    const float* W1 = (const float*)d_in[3];
    const float* b1 = (const float*)d_in[4];
    const float* W2 = (const float*)d_in[5];
    const float* b2 = (const float*)d_in[6];
    float* out = (float*)d_out;

    int N = in_sizes[0] / NFEAT;   // 100000
    int E = in_sizes[2];           // 1600000
    const int* srcI = ei;
    const int* dstI = ei + E;

    char* p = (char*)d_ws;
    auto alloc = [&](size_t bytes) {
        char* r = p;
        p += (bytes + 511) & ~(size_t)511;
        return r;
    };
    __bf16*   h1b = (__bf16*)alloc((size_t)N * NHID * 2);
    uint32_t* hu  = (uint32_t*)alloc((size_t)N * (NHID / 2) * 4);
    float*    h2  = (float*)alloc((size_t)N * NCLASS * 4);
    int*      cnt = (int*)alloc((size_t)N * 4);
    int*      rp  = (int*)alloc(((size_t)N + 1) * 4);
    int*      woff= (int*)alloc((size_t)N * 4);
    int2*     pay = (int2*)alloc((size_t)E * 8);
    __bf16*   W1f = (__bf16*)alloc((size_t)NFEAT * NHID * 2);
    int*      bs  = (int*)alloc(1024 * 4);
    int*      bo  = (int*)alloc(1024 * 4);

    int NB = (N + 1023) / 1024;    // 98 blocks (<=128 required by k_bscan)

    hipMemsetAsync(cnt, 0, (size_t)N * 4, stream);
    k_prep_w1<<<32, 256, 0, stream>>>(W1, W1f);

    int eb = (E + 255) / 256;
    k_count<<<eb, 256, 0, stream>>>(dstI, cnt, E);
    k_bsum<<<NB, 256, 0, stream>>>(cnt, bs, N);
    k_bscan<<<1, 128, 0, stream>>>(bs, bo, rp, NB, N);
    k_cscan<<<NB, 256, 0, stream>>>(cnt, bo, rp, woff, N);
    k_fill<<<eb, 256, 0, stream>>>(srcI, dstI, ew, woff, pay, E);

    k_gemm1<<<(N + 63) / 64, 256, 0, stream>>>(x, W1f, h1b, N);
    k_agg1<<<(N + 3) / 4, 256, 0, stream>>>((const uint32_t*)h1b, rp, pay, b1, hu, N);
    k_gemm2<<<(N + 15) / 16, 256, 0, stream>>>(hu, W2, h2, N);
    k_agg2<<<(int)(((size_t)N * 16 + 255) / 256), 256, 0, stream>>>(h2, rp, pay, b2, out, N);
}

// Round 4
// 614.848 us; speedup vs baseline: 1.2944x; 1.1168x over previous
//
#include <hip/hip_runtime.h>
#include <cstdint>
#include <cstddef>

// GNNGuard: 2-layer GCN, N=100000 nodes, E=1.6M edges, 512->128->16, log_softmax.
// R4: fix nontemporal-load type (native ext_vector float4, not HIP_vector_type);
// atomic-free fill via rank-from-count trick; bf16 h1/h; multi-block scan.

#define NFEAT 512
#define NHID 128
#define NCLASS 16

typedef __attribute__((ext_vector_type(8))) __bf16 bf16x8;
typedef __attribute__((ext_vector_type(4))) float f32x4;

// ---------------- W1 pre-pack into MFMA B-fragment order ----------------
// Layout: [kstep 0..15][nchunk 0..7][lane 0..63][j 0..7]
// value = bf16( W1[k = kstep*32 + (lane>>4)*8 + j][n = nchunk*16 + (lane&15)] )
__global__ void k_prep_w1(const float* __restrict__ W1, __bf16* __restrict__ W1f) {
    int t = blockIdx.x * 256 + threadIdx.x;
    if (t >= 16 * 8 * 64) return;
    int lane = t & 63;
    int nc = (t >> 6) & 7;
    int ks = t >> 9;
    int q = lane >> 4, col = lane & 15;
    __bf16* outp = W1f + (size_t)t * 8;
#pragma unroll
    for (int j = 0; j < 8; j++) {
        int k = ks * 32 + q * 8 + j;
        int n = nc * 16 + col;
        outp[j] = (__bf16)W1[k * NHID + n];
    }
}

// ---------------- CSR build ----------------
// Pass 1: histogram + save each edge's within-node rank (atomic return value).
__global__ void k_count_rank(const int* __restrict__ dst, int* __restrict__ cnt,
                             int* __restrict__ rank, int E) {
    int e = blockIdx.x * 256 + threadIdx.x;
    if (e < E) rank[e] = atomicAdd(&cnt[dst[e]], 1);
}

// Block-level partial sums: block b sums cnt[b*1024 .. b*1024+1023]
__global__ void k_bsum(const int* __restrict__ cnt, int* __restrict__ bs, int N) {
    int b = blockIdx.x, t = threadIdx.x;  // 256 threads
    int base = b * 1024 + t * 4;
    int s = 0;
    if (base + 3 < N) {
        int4 v = *(const int4*)(cnt + base);
        s = v.x + v.y + v.z + v.w;
    } else {
        for (int j = 0; j < 4; j++) { int i = base + j; if (i < N) s += cnt[i]; }
    }
#pragma unroll
    for (int o = 32; o; o >>= 1) s += __shfl_down(s, o);
    __shared__ int ws[4];
    if ((t & 63) == 0) ws[t >> 6] = s;
    __syncthreads();
    if (t == 0) bs[b] = ws[0] + ws[1] + ws[2] + ws[3];
}

// Scan of NB (<=128) block sums in one block of 128 threads; writes rp[N]=total.
__global__ void k_bscan(const int* __restrict__ bs, int* __restrict__ bo,
                        int* __restrict__ rp, int NB, int N) {
    int t = threadIdx.x;
    int lane = t & 63;
    int v = (t < NB) ? bs[t] : 0;
    int x = v;
#pragma unroll
    for (int o = 1; o < 64; o <<= 1) { int y = __shfl_up(x, o); if (lane >= o) x += y; }
    __shared__ int w0;
    if (t == 63) w0 = x;
    __syncthreads();
    int pre = (t >= 64) ? w0 : 0;
    if (t < NB) bo[t] = pre + x - v;
    if (t == 127) rp[N] = pre + x;  // grand total
}

// Per-block scan + add block offset; writes rp.
__global__ void k_cscan(const int* __restrict__ cnt, const int* __restrict__ bo,
                        int* __restrict__ rp, int N) {
    int b = blockIdx.x, t = threadIdx.x;  // 256 threads
    int base = b * 1024 + t * 4;
    int v0 = 0, v1 = 0, v2 = 0, v3 = 0;
    if (base + 3 < N) {
        int4 v = *(const int4*)(cnt + base);
        v0 = v.x; v1 = v.y; v2 = v.z; v3 = v.w;
    } else {
        if (base + 0 < N) v0 = cnt[base + 0];
        if (base + 1 < N) v1 = cnt[base + 1];
        if (base + 2 < N) v2 = cnt[base + 2];
        if (base + 3 < N) v3 = cnt[base + 3];
    }
    int s = v0 + v1 + v2 + v3;
    int x = s;
    int lane = t & 63, w = t >> 6;
#pragma unroll
    for (int o = 1; o < 64; o <<= 1) { int y = __shfl_up(x, o); if (lane >= o) x += y; }
    __shared__ int ws[4];
    if (lane == 63) ws[w] = x;
    __syncthreads();
    int pre = 0;
    for (int j = 0; j < w; j++) pre += ws[j];
    int excl = bo[b] + pre + x - s;
    int4 r;
    r.x = excl; r.y = excl + v0; r.z = r.y + v1; r.w = r.z + v2;
    if (base + 3 < N) {
        *(int4*)(rp + base) = r;
    } else {
        if (base + 0 < N) rp[base + 0] = r.x;
        if (base + 1 < N) rp[base + 1] = r.y;
        if (base + 2 < N) rp[base + 2] = r.z;
        if (base + 3 < N) rp[base + 3] = r.w;
    }
}

// Pass 2 (atomic-free): p = rp[dst] + rank; one 8B scatter store per edge.
__global__ void k_fill(const int* __restrict__ src, const int* __restrict__ dst,
                       const float* __restrict__ ew, const int* __restrict__ rank,
                       const int* __restrict__ rp, int2* __restrict__ pay, int E) {
    int e = blockIdx.x * 256 + threadIdx.x;
    if (e < E) {
        int d = dst[e];
        int p = rp[d] + rank[e];   // rp is read-only: L2-replicated, no line bouncing
        int2 pv;
        pv.x = src[e];
        pv.y = __float_as_int(ew[e]);
        pay[p] = pv;
    }
}

// ---------------- GEMM1: h1b[M,128] = bf16( x[M,512] @ W1 )  (bf16 MFMA, no LDS) ----
// C/D: col = lane&15, row = (lane>>4)*4 + reg   [verified layout, learn_hip m89/m91]
__global__ void k_gemm1(const float* __restrict__ x, const __bf16* __restrict__ W1f,
                        __bf16* __restrict__ h1b, int M) {
    int wave = threadIdx.x >> 6;
    int lane = threadIdx.x & 63;
    int q = lane >> 4;
    int col = lane & 15;
    int m0 = blockIdx.x * 64 + wave * 16 + col;  // A-operand row for this lane
    bool valid = (m0 < M);

    f32x4 acc[8];
#pragma unroll
    for (int n = 0; n < 8; n++) acc[n] = (f32x4)(0.0f);

    const bf16x8* Bf = (const bf16x8*)W1f;
    const float* arow = x + (size_t)m0 * NFEAT + q * 8;

    for (int kk = 0; kk < NFEAT; kk += 32) {
        bf16x8 af;
        if (valid) {
            const f32x4* ap = (const f32x4*)(arow + kk);
            f32x4 a0 = __builtin_nontemporal_load(ap);      // x streamed once: keep out of L2
            f32x4 a1 = __builtin_nontemporal_load(ap + 1);
            af[0] = (__bf16)a0[0]; af[1] = (__bf16)a0[1];
            af[2] = (__bf16)a0[2]; af[3] = (__bf16)a0[3];
            af[4] = (__bf16)a1[0]; af[5] = (__bf16)a1[1];
            af[6] = (__bf16)a1[2]; af[7] = (__bf16)a1[3];
        } else {
#pragma unroll
            for (int j = 0; j < 8; j++) af[j] = (__bf16)0.0f;
        }
        int kb = (kk >> 5) * 8;
#pragma unroll
        for (int n = 0; n < 8; n++) {
            bf16x8 bf = Bf[(size_t)(kb + n) * 64 + lane];
            acc[n] = __builtin_amdgcn_mfma_f32_16x16x32_bf16(af, bf, acc[n], 0, 0, 0);
        }
    }

    int rbase = blockIdx.x * 64 + wave * 16 + q * 4;
#pragma unroll
    for (int r = 0; r < 4; r++) {
        int row = rbase + r;
        if (row < M) {
            __bf16* op = h1b + (size_t)row * NHID + col;
#pragma unroll
            for (int n = 0; n < 8; n++) op[n * 16] = (__bf16)acc[n][r];
        }
    }
}

// ---------------- Aggregation layer 1 (pull, wave per node) + bias + ReLU -> bf16 ----
__global__ void k_agg1(const uint32_t* __restrict__ h1u, const int* __restrict__ rp,
                       const int2* __restrict__ pay, const float* __restrict__ b1,
                       uint32_t* __restrict__ hu, int N) {
    int gw = (int)((blockIdx.x * (unsigned)blockDim.x + threadIdx.x) >> 6);  // node id
    int lane = threadIdx.x & 63;
    if (gw >= N) return;
    int s0 = rp[gw], s1 = rp[gw + 1];
    float ax = 0.f, ay = 0.f;
    for (int base = s0; base < s1; base += 64) {
        int cnt = s1 - base;
        if (cnt > 64) cnt = 64;
        int sv = 0;
        float wv = 0.f;
        if (lane < cnt) {
            int2 pv = pay[base + lane];
            sv = pv.x;
            wv = __int_as_float(pv.y);
        }
        for (int j = 0; j < cnt; j++) {
            int s = __shfl(sv, j);
            float ww = __shfl(wv, j);
            uint32_t u = h1u[(size_t)s * 64 + lane];  // 2 bf16 features: 2*lane, 2*lane+1
            float fx = __uint_as_float(u << 16);
            float fy = __uint_as_float(u & 0xffff0000u);
            ax = fmaf(ww, fx, ax);
            ay = fmaf(ww, fy, ay);
        }
    }
    float2 bb = ((const float2*)b1)[lane];
    float ox = fmaxf(ax + bb.x, 0.f);
    float oy = fmaxf(ay + bb.y, 0.f);
    union { __bf16 h[2]; uint32_t u; } cvt;
    cvt.h[0] = (__bf16)ox;
    cvt.h[1] = (__bf16)oy;
    hu[(size_t)gw * 64 + lane] = cvt.u;
}

// ---------------- GEMM2: h2[M,16] = (bf16 h)[M,128] @ W2 ----------------
__global__ void k_gemm2(const uint32_t* __restrict__ hu, const float* __restrict__ W2,
                        float* __restrict__ h2, int N) {
    __shared__ float W2s[NHID * NCLASS];
    __shared__ float hs[16][NHID + 4];
    int t = threadIdx.x;
#pragma unroll
    for (int j = 0; j < 8; j++) W2s[t * 8 + j] = W2[t * 8 + j];
    int nb = blockIdx.x * 16;
    {
        // 16 rows x 64 uints = 1024 uints; 4 per thread
        int idx = t * 4;
        int row = idx >> 6;
        int kp = idx & 63;  // uint index within row (feature pair)
        if (nb + row < N) {
            const uint32_t* srcp = hu + (size_t)(nb + row) * 64 + kp;
#pragma unroll
            for (int j = 0; j < 4; j++) {
                uint32_t u = srcp[j];
                hs[row][(kp + j) * 2 + 0] = __uint_as_float(u << 16);
                hs[row][(kp + j) * 2 + 1] = __uint_as_float(u & 0xffff0000u);
            }
        } else {
#pragma unroll
            for (int j = 0; j < 4; j++) {
                hs[row][(kp + j) * 2 + 0] = 0.f;
                hs[row][(kp + j) * 2 + 1] = 0.f;
            }
        }
    }
    __syncthreads();
    int ni = t >> 4, c = t & 15;
    float acc = 0.f;
#pragma unroll 8
    for (int k = 0; k < NHID; k++) acc = fmaf(hs[ni][k], W2s[k * NCLASS + c], acc);
    if (nb + ni < N) h2[(size_t)(nb + ni) * NCLASS + c] = acc;
}

// ---------------- Aggregation layer 2 + bias + log_softmax (16 lanes / node) --------
__global__ void k_agg2(const float* __restrict__ h2, const int* __restrict__ rp,
                       const int2* __restrict__ pay, const float* __restrict__ b2,
                       float* __restrict__ out, int N) {
    int t = blockIdx.x * 256 + threadIdx.x;
    int node = t >> 4;
    int c = t & 15;
    if (node >= N) return;
    int s0 = rp[node], s1 = rp[node + 1];
    float acc = 0.f;
    for (int i = s0; i < s1; i++) {
        int2 pv = pay[i];
        acc = fmaf(__int_as_float(pv.y), h2[(size_t)pv.x * NCLASS + c], acc);
    }
    float o = acc + b2[c];
    float m = o;
#pragma unroll
    for (int d = 1; d < 16; d <<= 1) m = fmaxf(m, __shfl_xor(m, d));
    float e = expf(o - m);
    float ssum = e;
#pragma unroll
    for (int d = 1; d < 16; d <<= 1) ssum += __shfl_xor(ssum, d);
    out[(size_t)node * NCLASS + c] = o - m - logf(ssum);
}

extern "C" void kernel_launch(void* const* d_in, const int* in_sizes, int n_in,
                              void* d_out, int out_size, void* d_ws, size_t ws_size,
                              hipStream_t stream) {
    const float* x  = (const float*)d_in[0];
    const int*   ei = (const int*)d_in[1];
    const float* ew = (const float*)d_in[2];
    const float* W1 = (const float*)d_in[3];
    const float* b1 = (const float*)d_in[4];
    const float* W2 = (const float*)d_in[5];
    const float* b2 = (const float*)d_in[6];
    float* out = (float*)d_out;

    int N = in_sizes[0] / NFEAT;   // 100000
    int E = in_sizes[2];           // 1600000
    const int* srcI = ei;
    const int* dstI = ei + E;

    char* p = (char*)d_ws;
    auto alloc = [&](size_t bytes) {
        char* r = p;
        p += (bytes + 511) & ~(size_t)511;
        return r;
    };
    __bf16*   h1b  = (__bf16*)alloc((size_t)N * NHID * 2);
    uint32_t* hu   = (uint32_t*)alloc((size_t)N * (NHID / 2) * 4);
    float*    h2   = (float*)alloc((size_t)N * NCLASS * 4);
    int*      cnt  = (int*)alloc((size_t)N * 4);
    int*      rp   = (int*)alloc(((size_t)N + 1) * 4);
    int*      rank = (int*)alloc((size_t)E * 4);
    int2*     pay  = (int2*)alloc((size_t)E * 8);
    __bf16*   W1f  = (__bf16*)alloc((size_t)NFEAT * NHID * 2);
    int*      bs   = (int*)alloc(1024 * 4);
    int*      bo   = (int*)alloc(1024 * 4);

    int NB = (N + 1023) / 1024;    // 98 blocks (<=128 required by k_bscan)

    (void)hipMemsetAsync(cnt, 0, (size_t)N * 4, stream);
    k_prep_w1<<<32, 256, 0, stream>>>(W1, W1f);

    int eb = (E + 255) / 256;
    k_count_rank<<<eb, 256, 0, stream>>>(dstI, cnt, rank, E);
    k_bsum<<<NB, 256, 0, stream>>>(cnt, bs, N);
    k_bscan<<<1, 128, 0, stream>>>(bs, bo, rp, NB, N);
    k_cscan<<<NB, 256, 0, stream>>>(cnt, bo, rp, N);
    k_fill<<<eb, 256, 0, stream>>>(srcI, dstI, ew, rank, rp, pay, E);

    k_gemm1<<<(N + 63) / 64, 256, 0, stream>>>(x, W1f, h1b, N);
    k_agg1<<<(N + 3) / 4, 256, 0, stream>>>((const uint32_t*)h1b, rp, pay, b1, hu, N);
    k_gemm2<<<(N + 15) / 16, 256, 0, stream>>>(hu, W2, h2, N);
    k_agg2<<<(int)(((size_t)N * 16 + 255) / 256), 256, 0, stream>>>(h2, rp, pay, b2, out, N);
}